// Round 3
// baseline (391.732 us; speedup 1.0000x reference)
//
#include <hip/hip_runtime.h>

// Problem constants (from reference):
//   x:            [64, 30, 30, 1024] fp32
//   pattern_idx:  [64, 30, 30]       int32, values in [0, 64)
//   spatial_pe:   [30, 30, 512]      fp32
//   pattern_pe:   [64, 512]          fp32
//   out = x + concat(spatial_pe[h,w,:], pattern_pe[idx[b,h,w],:])
//
// Memory-bound: 236 MB read (x) + 236 MB write (out); pe tables are
// L2-resident (1.8 MB + 128 KB). Roofline ~75-85 us at 6.3 TB/s.
#define D4      256   // 1024 floats / 4 per float4
#define HALF4   128   // 512 floats / 4
#define HWPIX   900   // 30*30

// clang-native vector type: accepted by __builtin_nontemporal_* (HIP's
// float4 is a struct and is rejected by the builtin).
typedef float f4 __attribute__((ext_vector_type(4)));

__global__ __launch_bounds__(256) void cpe_kernel(
    const f4* __restrict__ x,
    const int* __restrict__ idx,
    const f4* __restrict__ spe,   // [900 * 128] f4
    const f4* __restrict__ ppe,   // [64  * 128] f4
    f4*       __restrict__ out,
    int n8)                        // number of f4-PAIRS
{
    int t = blockIdx.x * blockDim.x + threadIdx.x;
    if (t >= n8) return;
    int g   = t << 1;          // first f4 index of this thread's pair
    int c4  = g & (D4 - 1);    // f4 channel within pixel (even)
    int pix = g >> 8;          // global pixel (b*900 + h*30 + w)

    // x is read exactly once -> nontemporal keeps L2 for the pe tables
    f4 x0 = __builtin_nontemporal_load(&x[g]);
    f4 x1 = __builtin_nontemporal_load(&x[g + 1]);

    // Each wave spans 64 threads * 2 f4 = 128 f4 = exactly one half-pixel
    // -> branch is wave-uniform, idx[pix] is wave-uniform.
    f4 p0, p1;
    if (c4 < HALF4) {
        int hw = pix % HWPIX;                    // h*30+w (full 30x30 grid)
        const f4* s = &spe[hw * HALF4 + c4];
        p0 = s[0];
        p1 = s[1];
    } else {
        unsigned p = (unsigned)idx[pix] & 63u;   // ref applies % 64
        const f4* q = &ppe[p * HALF4 + (c4 - HALF4)];
        p0 = q[0];
        p1 = q[1];
    }

    f4 r0 = x0 + p0;   // ext_vector_type supports elementwise ops
    f4 r1 = x1 + p1;

    // write-once stream -> nontemporal store, no L2 write-allocate pollution
    __builtin_nontemporal_store(r0, &out[g]);
    __builtin_nontemporal_store(r1, &out[g + 1]);
}

extern "C" void kernel_launch(void* const* d_in, const int* in_sizes, int n_in,
                              void* d_out, int out_size, void* d_ws, size_t ws_size,
                              hipStream_t stream) {
    const f4* x   = (const f4*)d_in[0];
    const int* idx = (const int*)d_in[1];
    const f4* spe = (const f4*)d_in[2];
    const f4* ppe = (const f4*)d_in[3];
    f4*       out = (f4*)d_out;

    int n8 = out_size / 8;                // 7,372,800 f4-pairs
    int block = 256;
    int grid  = (n8 + block - 1) / block; // 28,800 blocks
    cpe_kernel<<<grid, block, 0, stream>>>(x, idx, spe, ppe, out, n8);
}